// Round 5
// baseline (460.170 us; speedup 1.0000x reference)
//
#include <hip/hip_runtime.h>
#include <hip/hip_bf16.h>
#include <math.h>

typedef __hip_bfloat16 bf16;
typedef short s16x8 __attribute__((ext_vector_type(8)));
typedef int   i32x4 __attribute__((ext_vector_type(4)));
typedef float f32x16 __attribute__((ext_vector_type(16)));

// Problem constants (DocREModel)
constexpr int B = 4, H = 12, C = 1024, D = 768, E = 30, M = 8, P = 600;
constexpr int NL = 97, RELS = 96, EMB = 768;
constexpr int N = B * P;          // 2400 pairs
constexpr int MG = 76;            // 2432/32 row groups (N padded to 2432)
constexpr int MGB = 20;           // per-batch row groups for rs GEMM (608->640)
constexpr int NPAD = 2560;        // padded N for logits partials (10 x 256-row tiles)
constexpr int LPAD = 128;         // padded label dim for logits partials
constexpr int NKBZ = 24;          // 12 kb x 2 z partial slabs

static __device__ __forceinline__ float b2f(bf16 x) { return __bfloat162float(x); }

// fast f32 -> bf16 bits (round-half-up; inputs finite)
static __device__ __forceinline__ short f2bfbits(float f) {
  unsigned u = __builtin_bit_cast(unsigned, f);
  return (short)((u + 0x8000u) >> 16);
}
static __device__ __forceinline__ float bf2f(short s) {
  return __builtin_bit_cast(float, ((unsigned)(unsigned short)s) << 16);
}

// dtype-agnostic load/store: BF=true -> buffer holds bf16, else float32
template <bool BF>
static __device__ __forceinline__ float ldf(const void* p, size_t i) {
  if (BF) return b2f(((const bf16*)p)[i]);
  return ((const float*)p)[i];
}
template <bool BF>
static __device__ __forceinline__ void stf(void* p, size_t i, float v) {
  if (BF) ((bf16*)p)[i] = __float2bfloat16(v);
  else    ((float*)p)[i] = v;
}

// dtype self-detect from mention_mask word 0. Reference guarantees
// mm[:, :, 0] == 1.0, and masks are exactly 0.0/1.0:
//   f32 : word0 = 0x3F800000            (never matches below)
//   bf16: word0 = 0x3F803F80 or 0x00003F80 (elem0=1.0 in low half)
static __device__ __forceinline__ bool detect_bf(const void* mm) {
  unsigned w = *(const unsigned*)mm;
  return (w == 0x00003F80u || w == 0x3F803F80u);
}

// packed f32x2 -> bf16x2 (RNE) — compiler can't form this from bit-tricks
static __device__ __forceinline__ int cvt_pk_bf16(float lo, float hi) {
  int r;
  asm("v_cvt_pk_bf16_f32 %0, %1, %2" : "=v"(r) : "v"(lo), "v"(hi));
  return r;
}

// ---------------------------------------------------------------------------
// Stage-1 bodies (input-only work): ent_emb, ent_att, prep_seq, prep_w,
// transpose_w. All read ONLY problem inputs -> run in one launch.
// ---------------------------------------------------------------------------
struct EntEmbSmem { int sidx[M]; float smask[M]; };
struct EntAttSmem { int sidx[M]; float smask[M]; float sinv; };
struct PrepSeqSmem { short Ss[16][776]; };
struct PrepWSmem  { short Ws[16][776]; };
struct TwSmem { float Ws[16][100]; };
union S1Smem { EntEmbSmem e; EntAttSmem a; PrepSeqSmem ps; PrepWSmem pw; TwSmem tw; };

template <bool BF>
static __device__ __forceinline__ void ent_emb_body(
    EntEmbSmem& s, const void* seq, const int* midx, const void* mmask,
    float* ent_emb, int be) {
  int b = be / E;
  if (threadIdx.x < M) {
    s.sidx[threadIdx.x] = midx[be * M + threadIdx.x] + 1;  // OFFSET
    s.smask[threadIdx.x] = ldf<BF>(mmask, be * M + threadIdx.x);
  }
  __syncthreads();
  for (int d = threadIdx.x; d < D; d += 256) {
    float v[M];
    float mx = -1e30f;
#pragma unroll
    for (int m = 0; m < M; m++) {
      v[m] = ldf<BF>(seq, ((size_t)(b * C + s.sidx[m])) * D + d);
      if (s.smask[m] != 0.0f) mx = fmaxf(mx, v[m]);
    }
    float sum = 0.f;
#pragma unroll
    for (int m = 0; m < M; m++)
      if (s.smask[m] != 0.0f) sum += expf(v[m] - mx);
    ent_emb[(size_t)be * D + d] = logf(sum) + mx;
  }
}

template <bool BF>
static __device__ __forceinline__ void ent_att_body(
    EntAttSmem& s, const void* att, const int* midx, const void* mmask,
    short* ent_att, int beh) {
  int h = beh % H;
  int be = beh / H;
  int b = be / E;
  if (threadIdx.x < M) {
    s.sidx[threadIdx.x] = midx[be * M + threadIdx.x] + 1;
    s.smask[threadIdx.x] = ldf<BF>(mmask, be * M + threadIdx.x);
  }
  __syncthreads();
  if (threadIdx.x == 0) {
    float cnt = 0.f;
    for (int m = 0; m < M; m++) cnt += s.smask[m];
    s.sinv = 1.0f / cnt;
  }
  __syncthreads();
  for (int c = threadIdx.x; c < C; c += 256) {
    float sum = 0.f;
#pragma unroll
    for (int m = 0; m < M; m++)
      if (s.smask[m] != 0.0f)
        sum += ldf<BF>(att, (((size_t)b * H + h) * C + s.sidx[m]) * C + c);
    ent_att[((size_t)be * H + h) * C + c] = f2bfbits(sum * s.sinv);
  }
}

template <bool BF>
static __device__ __forceinline__ void prep_seq_body(
    PrepSeqSmem& sm, const void* seq, short* Sf, short* Aht, int kc, int b) {
  int t = threadIdx.x;
  for (int e = t; e < 16 * D; e += 256) {
    int kk = e / D, c = e % D;
    sm.Ss[kk][c] = f2bfbits(ldf<BF>(seq, ((size_t)(b * C + kc * 16 + kk)) * D + c));
  }
  __syncthreads();
  int lane = t & 63, cg0 = t >> 6;
  int rr = lane & 31, half = lane >> 5;
#pragma unroll
  for (int q = 0; q < 6; q++) {
    int cg = cg0 + q * 4;
    int col = cg * 32 + rr;
    s16x8 v;
#pragma unroll
    for (int tt = 0; tt < 8; tt++) v[tt] = sm.Ss[half * 8 + tt][col];
    *(s16x8*)(Sf + ((((size_t)(b * 64 + kc)) * 24 + cg) * 64 + lane) * 8) = v;
  }
  if (t < 64) {
    s16x8 z = {0, 0, 0, 0, 0, 0, 0, 0};
    if ((t & 31) >= 24)
      *(s16x8*)(Aht + ((((size_t)(b * MGB + 18)) * 64 + kc) * 64 + t) * 8) = z;
    *(s16x8*)(Aht + ((((size_t)(b * MGB + 19)) * 64 + kc) * 64 + t) * 8) = z;
  }
}

template <bool BF>
static __device__ __forceinline__ void prep_w_body(
    PrepWSmem& sm, const void* headW, const void* headb,
    const void* tailW, const void* tailb,
    short* Wfh, short* Wft, float* bias_h, float* bias_t, int kc, int which) {
  const void* W = which ? tailW : headW;
  short* Wf = which ? Wft : Wfh;
  int t = threadIdx.x;
  for (int e = t; e < 16 * EMB; e += 256) {
    int kk = e / EMB, c = e % EMB;
    sm.Ws[kk][c] = f2bfbits(ldf<BF>(W, (size_t)(kc * 16 + kk) * EMB + c));
  }
  __syncthreads();
  int lane = t & 63, cg0 = t >> 6;
  int rr = lane & 31, half = lane >> 5;
#pragma unroll
  for (int q = 0; q < 6; q++) {
    int cg = cg0 + q * 4;
    int col = cg * 32 + rr;
    s16x8 v;
#pragma unroll
    for (int tt = 0; tt < 8; tt++) v[tt] = sm.Ws[half * 8 + tt][col];
    *(s16x8*)(Wf + (((size_t)kc * 24 + cg) * 64 + lane) * 8) = v;
  }
  if (kc == 0) {
    const void* bsrc = which ? tailb : headb;
    float* bdst = which ? bias_t : bias_h;
    for (int c = t; c < EMB; c += 256) bdst[c] = ldf<BF>(bsrc, c);
  }
}

template <bool BF>
static __device__ __forceinline__ void transpose_w_body(
    TwSmem& sm, const void* bilW, short* Wt, int s16i, int kb) {
  int t = threadIdx.x;
  size_t kbase = (size_t)kb * 4096 + s16i * 16;
  for (int e = t; e < 16 * NL; e += 256) {
    int rr = e / NL, l = e % NL;
    sm.Ws[rr][l] = ldf<BF>(bilW, (kbase + rr) * NL + l);
  }
  __syncthreads();
  int c = t >> 6, lane = t & 63;
  int half = lane >> 5, col = lane & 31;
  int label = c * 32 + col;
  s16x8 v;
#pragma unroll
  for (int tt = 0; tt < 8; tt++) {
    float x = (label < NL) ? sm.Ws[half * 8 + tt][label] : 0.f;
    v[tt] = f2bfbits(x);
  }
  size_t off = ((((size_t)kb * 256 + s16i) * 4 + c) * 64 + lane) * 8;
  *(s16x8*)(Wt + off) = v;
}

template <bool BF>
static __device__ __forceinline__ void stage1_body(
    S1Smem& sm, const void* seq, const void* att, const int* midx,
    const void* mmask, const void* headW, const void* headb,
    const void* tailW, const void* tailb, const void* bilW,
    float* ent_emb, short* ent_att, short* Sf, short* Aht,
    short* Wfh, short* Wft, float* bias_h, float* bias_t,
    short* Wt, float* riskarr) {
  int q = blockIdx.x;
  if (q == 0 && threadIdx.x < 2) riskarr[threadIdx.x] = 0.f;  // [0]=sum [1]=ctr
  if (q < B * E * H) {
    ent_att_body<BF>(sm.a, att, midx, mmask, ent_att, q);
  } else if (q < B * E * H + B * E) {
    ent_emb_body<BF>(sm.e, seq, midx, mmask, ent_emb, q - B * E * H);
  } else if (q < B * E * H + B * E + 256) {
    int r = q - (B * E * H + B * E);
    prep_seq_body<BF>(sm.ps, seq, Sf, Aht, r & 63, r >> 6);
  } else if (q < B * E * H + B * E + 256 + 192) {
    int r = q - (B * E * H + B * E + 256);
    prep_w_body<BF>(sm.pw, headW, headb, tailW, tailb, Wfh, Wft,
                    bias_h, bias_t, r % 96, r / 96);
  } else {
    int r = q - (B * E * H + B * E + 256 + 192);
    transpose_w_body<BF>(sm.tw, bilW, Wt, r & 255, r >> 8);
  }
}

__global__ __launch_bounds__(256) void k_stage1(
    const void* seq, const void* att, const int* midx, const void* mmask,
    const void* headW, const void* headb, const void* tailW, const void* tailb,
    const void* bilW,
    float* ent_emb, short* ent_att, short* Sf, short* Aht,
    short* Wfh, short* Wft, float* bias_h, float* bias_t,
    short* Wt, float* riskarr) {
  __shared__ S1Smem sm;
  if (detect_bf(mmask))
    stage1_body<true >(sm, seq, att, midx, mmask, headW, headb, tailW, tailb,
                       bilW, ent_emb, ent_att, Sf, Aht, Wfh, Wft, bias_h,
                       bias_t, Wt, riskarr);
  else
    stage1_body<false>(sm, seq, att, midx, mmask, headW, headb, tailW, tailb,
                       bilW, ent_emb, ent_att, Sf, Aht, Wfh, Wft, bias_h,
                       bias_t, Wt, riskarr);
}

// ---------------------------------------------------------------------------
// Stage 2: ht_att (-> Aht fragments) + prep_ahs (-> Ahs/Ats). Tiny LDS so
// the gather-heavy ht_att gets full occupancy.
// ---------------------------------------------------------------------------
static __device__ __forceinline__ void ht_att_body(
    float* red, const short* __restrict__ ent_att, const int* __restrict__ hts,
    short* __restrict__ Aht, int bp) {
  int b = bp / P, p = bp % P;
  int hi = hts[bp * 2 + 0], ti = hts[bp * 2 + 1];
  const short* hA = ent_att + ((size_t)(b * E + hi)) * H * C;
  const short* tA = ent_att + ((size_t)(b * E + ti)) * H * C;
  float v[2][2];
  float loc = 0.f;
#pragma unroll
  for (int q = 0; q < 2; q++) {
    int c = q * 512 + threadIdx.x * 2;
    float s0 = 0.f, s1 = 0.f;
#pragma unroll
    for (int h = 0; h < H; h++) {
      ushort2 a = *(const ushort2*)(hA + h * C + c);
      ushort2 t2 = *(const ushort2*)(tA + h * C + c);
      s0 += bf2f((short)a.x) * bf2f((short)t2.x);
      s1 += bf2f((short)a.y) * bf2f((short)t2.y);
    }
    v[q][0] = s0 * (1.0f / H);
    v[q][1] = s1 * (1.0f / H);
    loc += v[q][0] + v[q][1];
  }
  // wave reduce (6 shfl) + single barrier across 4 waves
#pragma unroll
  for (int off = 32; off > 0; off >>= 1) loc += __shfl_xor(loc, off, 64);
  if ((threadIdx.x & 63) == 0) red[threadIdx.x >> 6] = loc;
  __syncthreads();
  float inv = 1.0f / (red[0] + red[1] + red[2] + red[3] + 1e-5f);
  int mg = p >> 5, rr = p & 31;
#pragma unroll
  for (int q = 0; q < 2; q++) {
    int c = q * 512 + threadIdx.x * 2;
    int kc = c >> 4, half = (c >> 3) & 1, tt = c & 7;
    short* dst =
        Aht + ((((size_t)(b * MGB + mg)) * 64 + kc) * 64 + half * 32 + rr) * 8 + tt;
    dst[0] = f2bfbits(v[q][0] * inv);
    dst[1] = f2bfbits(v[q][1] * inv);
  }
}

static __device__ __forceinline__ void prep_ahs_body(
    const float* __restrict__ ent_emb, const int* __restrict__ hts,
    short* __restrict__ Ahs, short* __restrict__ Ats, int mg, int which) {
  short* Adst = which ? Ats : Ahs;
  int t = threadIdx.x, lane = t & 63, kc0 = t >> 6;
  int rr = lane & 31, half = lane >> 5;
  int row = mg * 32 + rr;
  bool valid = row < N;
  size_t base = 0;
  if (valid) {
    int b = row / P, p = row % P;
    int e = hts[(b * P + p) * 2 + which];
    base = (size_t)(b * E + e) * D;
  }
#pragma unroll
  for (int q = 0; q < 12; q++) {
    int kc = kc0 + q * 4;
    s16x8 v = {0, 0, 0, 0, 0, 0, 0, 0};
    if (valid) {
      const float* p = ent_emb + base + kc * 16 + half * 8;
      float4 v0 = *(const float4*)p;
      float4 v1 = *(const float4*)(p + 4);
      v[0] = f2bfbits(v0.x); v[1] = f2bfbits(v0.y);
      v[2] = f2bfbits(v0.z); v[3] = f2bfbits(v0.w);
      v[4] = f2bfbits(v1.x); v[5] = f2bfbits(v1.y);
      v[6] = f2bfbits(v1.z); v[7] = f2bfbits(v1.w);
    }
    *(s16x8*)(Adst + (((size_t)mg * 48 + kc) * 64 + lane) * 8) = v;
  }
}

__global__ __launch_bounds__(256) void k_stage2(
    const short* __restrict__ ent_att, const float* __restrict__ ent_emb,
    const int* __restrict__ hts,
    short* __restrict__ Aht, short* __restrict__ Ahs, short* __restrict__ Ats) {
  __shared__ float red[4];
  int q = blockIdx.x;
  if (q < B * P) {
    ht_att_body(red, ent_att, hts, Aht, q);
  } else {
    int r = q - B * P;
    prep_ahs_body(ent_emb, hts, Ahs, Ats, r % MG, r / MG);
  }
}

// ---------------------------------------------------------------------------
// Kernel: rs = ht_att @ seq via MFMA 32x32x16 bf16. Also zeroes the Ars
// pad row-group (mg = MG-1) — must happen after ent_att is dead (it aliases),
// and before k_head_mfma reads it: this kernel boundary satisfies both.
// ---------------------------------------------------------------------------
__global__ __launch_bounds__(256) void k_rs_mfma(
    const short* __restrict__ Aht, const short* __restrict__ Sf,
    short* __restrict__ Ars) {
  int mt = blockIdx.x, nt = blockIdx.y, b = blockIdx.z;
  int t = threadIdx.x, w = t >> 6, lane = t & 63;
  int half = lane >> 5, r = lane & 31;
  int wm = w >> 1, wn = w & 1;
  int mg = mt * 2 + wm;          // 0..19
  int cg0 = nt * 4 + wn * 2;     // 0..22, 2 cg per wave

  // zero Ars pad row-group mg=75: 48*64*8 = 24576 shorts, contiguous
  if (b == 0 && mt == 0) {
    int zt = nt * 256 + t;  // 0..1535
    s16x8 zz = {0, 0, 0, 0, 0, 0, 0, 0};
    for (int i = zt; i < 3072; i += 1536)
      *(s16x8*)(Ars + (size_t)1843200 + (size_t)i * 8) = zz;
  }

  f32x16 acc[2];
#pragma unroll
  for (int j = 0; j < 2; j++)
#pragma unroll
    for (int e = 0; e < 16; e++) acc[j][e] = 0.f;

  const short* abase = Aht + (((size_t)(b * MGB + mg)) * 64 * 64 + lane) * 8;
  const short* bbase = Sf + ((((size_t)(b * 64)) * 24 + cg0) * 64 + lane) * 8;

#pragma unroll 4
  for (int kc = 0; kc < 64; kc++) {
    s16x8 a  = *(const s16x8*)(abase + (size_t)kc * 64 * 8);
    s16x8 b0 = *(const s16x8*)(bbase + ((size_t)kc * 24 + 0) * 64 * 8);
    s16x8 b1 = *(const s16x8*)(bbase + ((size_t)kc * 24 + 1) * 64 * 8);
    acc[0] = __builtin_amdgcn_mfma_f32_32x32x16_bf16(a, b0, acc[0], 0, 0, 0);
    acc[1] = __builtin_amdgcn_mfma_f32_32x32x16_bf16(a, b1, acc[1], 0, 0, 0);
  }

  // C/D: col = lane&31, row = (reg&3) + 8*(reg>>2) + 4*half
#pragma unroll
  for (int j = 0; j < 2; j++) {
    int col = (cg0 + j) * 32 + r;
    int kcd = col >> 4, hd = (col >> 3) & 1, ttd = col & 7;
#pragma unroll
    for (int reg = 0; reg < 16; reg++) {
      int p = mg * 32 + (reg & 3) + 8 * (reg >> 2) + 4 * half;
      if (p < P) {
        int n = b * P + p;
        Ars[((((size_t)(n >> 5)) * 48 + kcd) * 64 + hd * 32 + (n & 31)) * 8 + ttd] =
            f2bfbits(acc[j][reg]);
      }
    }
  }
}

// ---------------------------------------------------------------------------
// Kernel: hz/tz = tanh(A @ W + bias) via MFMA, output bf16.
// ---------------------------------------------------------------------------
__global__ __launch_bounds__(256) void k_head_mfma(
    const short* __restrict__ Ahs, const short* __restrict__ Ats,
    const short* __restrict__ Ars,
    const short* __restrict__ Wfh, const short* __restrict__ Wft,
    const float* __restrict__ bias_h, const float* __restrict__ bias_t,
    short* __restrict__ hz, short* __restrict__ tz) {
  int mt = blockIdx.x, nt = blockIdx.y, which = blockIdx.z;
  const short* Ahead = which ? Ats : Ahs;
  const short* Wf = which ? Wft : Wfh;
  const float* bias = which ? bias_t : bias_h;
  short* out = which ? tz : hz;

  int t = threadIdx.x, w = t >> 6, lane = t & 63;
  int half = lane >> 5, r = lane & 31;
  int wm = w >> 1, wn = w & 1;
  int mg0 = mt * 4 + wm * 2;
  int cg0 = nt * 4 + wn * 2;

  f32x16 acc[2][2];
#pragma unroll
  for (int i = 0; i < 2; i++)
#pragma unroll
    for (int j = 0; j < 2; j++)
#pragma unroll
      for (int e = 0; e < 16; e++) acc[i][j][e] = 0.f;

#pragma unroll 4
  for (int kc = 0; kc < 48; kc++) {
    s16x8 a0 = *(const s16x8*)(Ahead + (((size_t)(mg0 + 0) * 48 + kc) * 64 + lane) * 8);
    s16x8 a1 = *(const s16x8*)(Ahead + (((size_t)(mg0 + 1) * 48 + kc) * 64 + lane) * 8);
    s16x8 b0 = *(const s16x8*)(Wf + (((size_t)kc * 24 + cg0 + 0) * 64 + lane) * 8);
    s16x8 b1 = *(const s16x8*)(Wf + (((size_t)kc * 24 + cg0 + 1) * 64 + lane) * 8);
    acc[0][0] = __builtin_amdgcn_mfma_f32_32x32x16_bf16(a0, b0, acc[0][0], 0, 0, 0);
    acc[0][1] = __builtin_amdgcn_mfma_f32_32x32x16_bf16(a0, b1, acc[0][1], 0, 0, 0);
    acc[1][0] = __builtin_amdgcn_mfma_f32_32x32x16_bf16(a1, b0, acc[1][0], 0, 0, 0);
    acc[1][1] = __builtin_amdgcn_mfma_f32_32x32x16_bf16(a1, b1, acc[1][1], 0, 0, 0);
  }
#pragma unroll 4
  for (int kc = 0; kc < 48; kc++) {
    s16x8 a0 = *(const s16x8*)(Ars + (((size_t)(mg0 + 0) * 48 + kc) * 64 + lane) * 8);
    s16x8 a1 = *(const s16x8*)(Ars + (((size_t)(mg0 + 1) * 48 + kc) * 64 + lane) * 8);
    s16x8 b0 = *(const s16x8*)(Wf + (((size_t)(kc + 48) * 24 + cg0 + 0) * 64 + lane) * 8);
    s16x8 b1 = *(const s16x8*)(Wf + (((size_t)(kc + 48) * 24 + cg0 + 1) * 64 + lane) * 8);
    acc[0][0] = __builtin_amdgcn_mfma_f32_32x32x16_bf16(a0, b0, acc[0][0], 0, 0, 0);
    acc[0][1] = __builtin_amdgcn_mfma_f32_32x32x16_bf16(a0, b1, acc[0][1], 0, 0, 0);
    acc[1][0] = __builtin_amdgcn_mfma_f32_32x32x16_bf16(a1, b0, acc[1][0], 0, 0, 0);
    acc[1][1] = __builtin_amdgcn_mfma_f32_32x32x16_bf16(a1, b1, acc[1][1], 0, 0, 0);
  }

#pragma unroll
  for (int i = 0; i < 2; i++) {
    int rowbase = (mg0 + i) * 32 + 4 * half;
#pragma unroll
    for (int j = 0; j < 2; j++) {
      int col = (cg0 + j) * 32 + r;
      float bv = bias[col];
#pragma unroll
      for (int reg = 0; reg < 16; reg++) {
        int n = rowbase + (reg & 3) + 8 * (reg >> 2);
        if (n < N) out[(size_t)n * EMB + col] = f2bfbits(tanhf(acc[i][j][reg] + bv));
      }
    }
  }
}

// ---------------------------------------------------------------------------
// Kernel: bilinear logits via MFMA 32x32x16 bf16, A generated on the fly
// with v_cvt_pk_bf16_f32. TWO 128-row n-tiles per block: each Wt B-fragment
// feeds 2 MFMAs -> B-fetch traffic halves (it was the bound). Partials are
// per-(kb,z) slabs; unconditional stores into padded [NPAD][LPAD] space.
// ---------------------------------------------------------------------------
__global__ __launch_bounds__(256) void k_logits_mfma(
    const short* __restrict__ hz, const short* __restrict__ tz,
    const short* __restrict__ Wt, float* __restrict__ part) {
  int kb = blockIdx.x;
  int mb2 = blockIdx.y;  // 256-row tile pair
  int z = blockIdx.z;    // i-half
  int t = threadIdx.x;
  int w = t >> 6, lane = t & 63;
  int half = lane >> 5, r = lane & 31;
  int nb2 = mb2 * 256;

  __shared__ float hzs[2][128][33];
  {
    int row = t >> 1;
    int col0 = (t & 1) * 16;
#pragma unroll
    for (int u = 0; u < 2; u++) {
      int n = nb2 + u * 128 + row;
#pragma unroll
      for (int q = 0; q < 2; q++) {
        float vv[8] = {0.f, 0.f, 0.f, 0.f, 0.f, 0.f, 0.f, 0.f};
        if (n < N) {
          s16x8 v = *(const s16x8*)(hz + (size_t)n * EMB + kb * 64 + z * 32 + col0 + q * 8);
#pragma unroll
          for (int tt = 0; tt < 8; tt++) vv[tt] = bf2f(v[tt]);
        }
#pragma unroll
        for (int tt = 0; tt < 8; tt++) hzs[u][row][col0 + q * 8 + tt] = vv[tt];
      }
    }
  }
  float tzr[2][4][8];
  {
#pragma unroll
    for (int u = 0; u < 2; u++) {
      int n = nb2 + u * 128 + w * 32 + r;
#pragma unroll
      for (int q4 = 0; q4 < 4; q4++) {
        s16x8 v = {0, 0, 0, 0, 0, 0, 0, 0};
        if (n < N) v = *(const s16x8*)(tz + (size_t)n * EMB + kb * 64 + q4 * 16 + half * 8);
#pragma unroll
        for (int tt = 0; tt < 8; tt++) tzr[u][q4][tt] = bf2f(v[tt]);
      }
    }
  }
  __syncthreads();

  f32x16 acc[2][4];
#pragma unroll
  for (int u = 0; u < 2; u++)
#pragma unroll
    for (int c = 0; c < 4; c++)
#pragma unroll
      for (int e = 0; e < 16; e++) acc[u][c][e] = 0.f;

  const int wrow = w * 32 + r;
  const short* wbase = Wt + (((size_t)kb * 256) * 4) * 64 * 8 + (size_t)lane * 8;

#pragma unroll 2
  for (int ii = 0; ii < 32; ii++) {
    int i = z * 32 + ii;
    float hv0 = hzs[0][wrow][ii];
    float hv1 = hzs[1][wrow][ii];
#pragma unroll
    for (int q4 = 0; q4 < 4; q4++) {
      i32x4 pk0, pk1;
#pragma unroll
      for (int u = 0; u < 4; u++) {
        pk0[u] = cvt_pk_bf16(hv0 * tzr[0][q4][2 * u], hv0 * tzr[0][q4][2 * u + 1]);
        pk1[u] = cvt_pk_bf16(hv1 * tzr[1][q4][2 * u], hv1 * tzr[1][q4][2 * u + 1]);
      }
      s16x8 af0 = __builtin_bit_cast(s16x8, pk0);
      s16x8 af1 = __builtin_bit_cast(s16x8, pk1);
      int s16i = i * 4 + q4;
#pragma unroll
      for (int c = 0; c < 4; c++) {
        s16x8 bf = *(const s16x8*)(wbase + ((size_t)s16i * 4 + c) * 64 * 8);
        acc[0][c] = __builtin_amdgcn_mfma_f32_32x32x16_bf16(af0, bf, acc[0][c], 0, 0, 0);
        acc[1][c] = __builtin_amdgcn_mfma_f32_32x32x16_bf16(af1, bf, acc[1][c], 0, 0, 0);
      }
    }
  }

  // unconditional partial stores: part[kb*2+z][n][label]
#pragma unroll
  for (int u = 0; u < 2; u++) {
    float* pbase = part + ((size_t)(kb * 2 + z) * NPAD + nb2 + u * 128 + w * 32) * LPAD;
#pragma unroll
    for (int c = 0; c < 4; c++) {
      int label = c * 32 + r;
#pragma unroll
      for (int reg = 0; reg < 16; reg++) {
        int row = (reg & 3) + 8 * (reg >> 2) + 4 * half;
        pbase[(size_t)row * LPAD + label] = acc[u][c][reg];
      }
    }
  }
}

// ---------------------------------------------------------------------------
// Kernel: reduce 24 partials + bias -> final logits_f AND out[1..].
// ---------------------------------------------------------------------------
template <bool BF>
static __device__ __forceinline__ void reduce_body(
    const float* __restrict__ part, const void* bilb,
    float* __restrict__ logits_f, void* out) {
  int idx = blockIdx.x * 256 + threadIdx.x;
  if (idx >= N * NL) return;
  int n = idx / NL, l = idx % NL;
  float s = ldf<BF>(bilb, l);
  const float* p = part + (size_t)n * LPAD + l;
#pragma unroll
  for (int k = 0; k < NKBZ; k++) s += p[(size_t)k * NPAD * LPAD];
  logits_f[idx] = s;
  stf<BF>(out, (size_t)idx + 1, s);  // out[0] = risk, out[1..] = logits
}

__global__ __launch_bounds__(256) void k_reduce(
    const float* __restrict__ part, const void* bilb, const void* mmask,
    float* __restrict__ logits_f, void* out) {
  if (detect_bf(mmask)) reduce_body<true >(part, bilb, logits_f, out);
  else                  reduce_body<false>(part, bilb, logits_f, out);
}

// ---------------------------------------------------------------------------
// Kernel: per-relation PU risk on final (biased) logits; last block writes
// the total into out[0].
// ---------------------------------------------------------------------------
struct RiskSmem { float red[5][256]; };

template <bool BF>
static __device__ __forceinline__ void risk_body(
    RiskSmem& sm, const float* logits_f, const int* labels,
    const void* priors_l, const void* priors_o,
    void* out, float* risk_ws, int r) {
  int t = threadIdx.x;
  float s_neg = 0.f, s_pp = 0.f, s_pn = 0.f, c_neg = 0.f, c_pos = 0.f;
  for (int n = t; n < N; n += 256) {
    float sc = logits_f[(size_t)n * NL + (r + 1)] - logits_f[(size_t)n * NL];
    bool pos = labels[(size_t)n * NL + (r + 1)] == 1;
    float ln = 0.25f * (sc + 1.f) * (sc + 1.f);  // sign=-1
    float lp = 0.25f * (sc - 1.f) * (sc - 1.f);  // sign=+1
    if (pos) { c_pos += 1.f; s_pp += lp; s_pn += ln; }
    else     { c_neg += 1.f; s_neg += ln; }
  }
  sm.red[0][t] = s_neg; sm.red[1][t] = s_pp; sm.red[2][t] = s_pn;
  sm.red[3][t] = c_neg; sm.red[4][t] = c_pos;
  __syncthreads();
  for (int off = 128; off > 0; off >>= 1) {
    if (t < off) {
#pragma unroll
      for (int q = 0; q < 5; q++) sm.red[q][t] += sm.red[q][t + off];
    }
    __syncthreads();
  }
  if (t == 0) {
    float sq_neg   = sm.red[3][0] > 0.f ? sm.red[0][0] / fmaxf(sm.red[3][0], 1.f) : 0.f;
    float sq_pos_p = sm.red[4][0] > 0.f ? sm.red[1][0] / fmaxf(sm.red[4][0], 1.f) : 0.f;
    float sq_pos_n = sm.red[4][0] > 0.f ? sm.red[2][0] / fmaxf(sm.red[4][0], 1.f) : 0.f;
    float po = ldf<BF>(priors_o, r), pl = ldf<BF>(priors_l, r);
    float weight = sqrtf((1.f - po) / po);
    float pu = (po - pl) / (1.f - pl);
    float risk1 = (1.f - po) / (1.f - pu) * sq_neg - (pu - pu * po) / (1.f - pu) * sq_pos_n;
    float risk2 = po * sq_pos_p * weight;
    float riskv = (risk1 < 0.f) ? -risk1 : (risk1 + risk2);  // BETA=0, GAMMA=1
    atomicAdd(&risk_ws[0], riskv);
    __threadfence();
    unsigned prev = atomicAdd((unsigned int*)(risk_ws + 1), 1u);
    if (prev == RELS - 1) {
      __threadfence();
      float total = atomicAdd(&risk_ws[0], 0.0f);  // atomic read at coherent point
      stf<BF>(out, 0, total);
    }
  }
}

__global__ __launch_bounds__(256) void k_risk(
    const float* __restrict__ logits_f, const int* __restrict__ labels,
    const void* priors_l, const void* priors_o, const void* mmask,
    void* out, float* risk_ws) {
  __shared__ RiskSmem sm;
  if (detect_bf(mmask))
    risk_body<true >(sm, logits_f, labels, priors_l, priors_o, out, risk_ws, blockIdx.x);
  else
    risk_body<false>(sm, logits_f, labels, priors_l, priors_o, out, risk_ws, blockIdx.x);
}

// ---------------------------------------------------------------------------
extern "C" void kernel_launch(void* const* d_in, const int* in_sizes, int n_in,
                              void* d_out, int out_size, void* d_ws, size_t ws_size,
                              hipStream_t stream) {
  const void* seq    = d_in[0];
  const void* att    = d_in[1];
  const int*  midx   = (const int*)d_in[2];
  const void* mmask  = d_in[3];
  const int*  hts    = (const int*)d_in[4];
  const int*  labels = (const int*)d_in[5];
  const void* pl     = d_in[6];
  const void* po     = d_in[7];
  const void* headW  = d_in[8];
  const void* headb  = d_in[9];
  const void* tailW  = d_in[10];
  const void* tailb  = d_in[11];
  const void* bilW   = d_in[12];
  const void* bilb   = d_in[13];

  // Workspace layout (floats after 64B header); ~80 MB total (ws is 768 MiB
  // per the harness poison fills). regionA = [ent_att(bf16) | Aht | Sf]:
  //   ent_att dead after stage2(ht_att); Aht/Sf dead after k_rs_mfma.
  //   Ars aliases regionA start (pad zeroed inside k_rs_mfma).
  //   Wt and logits partials live in dedicated space (no aliasing).
  float* w = (float*)d_ws + 16;
  float* ent_emb  = w;                                     //    92,160 f
  short* hz       = (short*)(ent_emb + (size_t)B * E * D); // 1,843,200 s
  short* tz       = hz + (size_t)N * EMB;                  // 1,843,200 s
  float* logits_f = (float*)(tz + (size_t)N * EMB);        //   232,800 f
  float* riskarr  = logits_f + (size_t)N * NL;             //       128 f
  float* bias_h   = riskarr + 128;                         //       768 f
  float* bias_t   = bias_h + 768;                          //       768 f
  float* regionA  = bias_t + 768;                          // 3,620,864 f
  short* ent_att  = (short*)regionA;                       // 1,474,560 s (bf16)
  short* Aht      = ent_att + 1474560;                     // 2,621,440 s
  short* Sf       = Aht + (size_t)B * MGB * 64 * 512;      // 3,145,728 s
  short* Ars      = (short*)regionA;                       // 1,867,776 s (alias)
  float* after    = regionA + 3620864;
  short* Ahs      = (short*)after;                         // 1,867,776 s
  short* Ats      = Ahs + (size_t)MG * 48 * 512;           // 1,867,776 s
  short* Wfh      = Ats + (size_t)MG * 48 * 512;           // 1,179,648 s
  short* Wft      = Wfh + (size_t)96 * 24 * 512;           // 1,179,648 s
  float* after2   = after + 3047424;
  short* Wt       = (short*)after2;                        // 6,291,456 s
  float* part     = after2 + 3145728;                      // 7,864,320 f

  // 7 launches; all input-only prep front-loaded into stage1.
  k_stage1<<<B * E * H + B * E + 256 + 192 + 3072, 256, 0, stream>>>(
      seq, att, midx, mmask, headW, headb, tailW, tailb, bilW,
      ent_emb, ent_att, Sf, Aht, Wfh, Wft, bias_h, bias_t, Wt, riskarr);
  k_stage2<<<B * P + 2 * MG, 256, 0, stream>>>(ent_att, ent_emb, hts,
                                               Aht, Ahs, Ats);
  k_rs_mfma<<<dim3(10, 6, B), 256, 0, stream>>>(Aht, Sf, Ars);
  k_head_mfma<<<dim3(19, 6, 2), 256, 0, stream>>>(Ahs, Ats, Ars, Wfh, Wft,
                                                  bias_h, bias_t, hz, tz);
  k_logits_mfma<<<dim3(12, 10, 2), 256, 0, stream>>>(hz, tz, Wt, part);
  k_reduce<<<(N * NL + 255) / 256, 256, 0, stream>>>(part, bilb, mmask,
                                                     logits_f, d_out);
  k_risk<<<RELS, 256, 0, stream>>>(logits_f, labels, pl, po, mmask,
                                   d_out, riskarr);
}

// Round 7
// 445.050 us; speedup vs baseline: 1.0340x; 1.0340x over previous
//
#include <hip/hip_runtime.h>
#include <hip/hip_bf16.h>
#include <math.h>

typedef __hip_bfloat16 bf16;
typedef short s16x8 __attribute__((ext_vector_type(8)));
typedef int   i32x4 __attribute__((ext_vector_type(4)));
typedef float f32x16 __attribute__((ext_vector_type(16)));

// Problem constants (DocREModel)
constexpr int B = 4, H = 12, C = 1024, D = 768, E = 30, M = 8, P = 600;
constexpr int NL = 97, RELS = 96, EMB = 768;
constexpr int N = B * P;          // 2400 pairs
constexpr int MG = 76;            // 2432/32 row groups (N padded to 2432)
constexpr int MGB = 20;           // per-batch row groups for rs GEMM (608->640)
constexpr int NPAD = 2432;        // padded N for logits partials
constexpr int LPAD = 128;        // padded label dim for logits partials
constexpr int NKBZ = 24;          // 12 kb x 2 z partial slabs

constexpr int NB_S1 = B * E * H + B * E + 256 + 192 + 3072;  // 5080
constexpr int NB_S2 = B * P + 2 * MG;                        // 2552
constexpr int NB_RD = (N * NL + 255) / 256;                  // 910

static __device__ __forceinline__ float b2f(bf16 x) { return __bfloat162float(x); }

// fast f32 -> bf16 bits (round-half-up; inputs finite)
static __device__ __forceinline__ short f2bfbits(float f) {
  unsigned u = __builtin_bit_cast(unsigned, f);
  return (short)((u + 0x8000u) >> 16);
}
static __device__ __forceinline__ float bf2f(short s) {
  return __builtin_bit_cast(float, ((unsigned)(unsigned short)s) << 16);
}

// dtype-agnostic load/store: BF=true -> buffer holds bf16, else float32
template <bool BF>
static __device__ __forceinline__ float ldf(const void* p, size_t i) {
  if (BF) return b2f(((const bf16*)p)[i]);
  return ((const float*)p)[i];
}
template <bool BF>
static __device__ __forceinline__ void stf(void* p, size_t i, float v) {
  if (BF) ((bf16*)p)[i] = __float2bfloat16(v);
  else    ((float*)p)[i] = v;
}

// dtype self-detect from mention_mask word 0 (mm[...,0]==1.0 guaranteed).
static __device__ __forceinline__ bool detect_bf(const void* mm) {
  unsigned w = *(const unsigned*)mm;
  return (w == 0x00003F80u || w == 0x3F803F80u);
}

// packed f32x2 -> bf16x2 (RNE)
static __device__ __forceinline__ int cvt_pk_bf16(float lo, float hi) {
  int r;
  asm("v_cvt_pk_bf16_f32 %0, %1, %2" : "=v"(r) : "v"(lo), "v"(hi));
  return r;
}

// ---------------------------------------------------------------------------
// Shared-memory structs
// ---------------------------------------------------------------------------
struct EntEmbSmem { int sidx[M]; float smask[M]; };
struct EntAttSmem { int sidx[M]; float smask[M]; float sinv; };
struct PrepSeqSmem { short Ss[16][776]; };
struct PrepWSmem  { short Ws[16][776]; };
struct TwSmem { float Ws[16][100]; };
union S1Smem { EntEmbSmem e; EntAttSmem a; PrepSeqSmem ps; PrepWSmem pw; TwSmem tw; };
struct RiskSmem { float red[5][256]; };

// ---------------------------------------------------------------------------
// Stage-1 bodies (input-only): ent_emb, ent_att, prep_seq, prep_w, transpose_w
// ---------------------------------------------------------------------------
template <bool BF>
static __device__ __forceinline__ void ent_emb_body(
    EntEmbSmem& s, const void* seq, const int* midx, const void* mmask,
    float* ent_emb, int be) {
  int b = be / E;
  if (threadIdx.x < M) {
    s.sidx[threadIdx.x] = midx[be * M + threadIdx.x] + 1;  // OFFSET
    s.smask[threadIdx.x] = ldf<BF>(mmask, be * M + threadIdx.x);
  }
  __syncthreads();
  for (int d = threadIdx.x; d < D; d += 256) {
    float v[M];
    float mx = -1e30f;
#pragma unroll
    for (int m = 0; m < M; m++) {
      v[m] = ldf<BF>(seq, ((size_t)(b * C + s.sidx[m])) * D + d);
      if (s.smask[m] != 0.0f) mx = fmaxf(mx, v[m]);
    }
    float sum = 0.f;
#pragma unroll
    for (int m = 0; m < M; m++)
      if (s.smask[m] != 0.0f) sum += expf(v[m] - mx);
    ent_emb[(size_t)be * D + d] = logf(sum) + mx;
  }
}

template <bool BF>
static __device__ __forceinline__ void ent_att_body(
    EntAttSmem& s, const void* att, const int* midx, const void* mmask,
    short* ent_att, int beh) {
  int h = beh % H;
  int be = beh / H;
  int b = be / E;
  if (threadIdx.x < M) {
    s.sidx[threadIdx.x] = midx[be * M + threadIdx.x] + 1;
    s.smask[threadIdx.x] = ldf<BF>(mmask, be * M + threadIdx.x);
  }
  __syncthreads();
  if (threadIdx.x == 0) {
    float cnt = 0.f;
    for (int m = 0; m < M; m++) cnt += s.smask[m];
    s.sinv = 1.0f / cnt;
  }
  __syncthreads();
  for (int c = threadIdx.x; c < C; c += 256) {
    float sum = 0.f;
#pragma unroll
    for (int m = 0; m < M; m++)
      if (s.smask[m] != 0.0f)
        sum += ldf<BF>(att, (((size_t)b * H + h) * C + s.sidx[m]) * C + c);
    ent_att[((size_t)be * H + h) * C + c] = f2bfbits(sum * s.sinv);
  }
}

template <bool BF>
static __device__ __forceinline__ void prep_seq_body(
    PrepSeqSmem& sm, const void* seq, short* Sf, short* Aht, int kc, int b) {
  int t = threadIdx.x;
  for (int e = t; e < 16 * D; e += 256) {
    int kk = e / D, c = e % D;
    sm.Ss[kk][c] = f2bfbits(ldf<BF>(seq, ((size_t)(b * C + kc * 16 + kk)) * D + c));
  }
  __syncthreads();
  int lane = t & 63, cg0 = t >> 6;
  int rr = lane & 31, half = lane >> 5;
#pragma unroll
  for (int q = 0; q < 6; q++) {
    int cgi = cg0 + q * 4;
    int col = cgi * 32 + rr;
    s16x8 v;
#pragma unroll
    for (int tt = 0; tt < 8; tt++) v[tt] = sm.Ss[half * 8 + tt][col];
    *(s16x8*)(Sf + ((((size_t)(b * 64 + kc)) * 24 + cgi) * 64 + lane) * 8) = v;
  }
  if (t < 64) {
    s16x8 z = {0, 0, 0, 0, 0, 0, 0, 0};
    if ((t & 31) >= 24)
      *(s16x8*)(Aht + ((((size_t)(b * MGB + 18)) * 64 + kc) * 64 + t) * 8) = z;
    *(s16x8*)(Aht + ((((size_t)(b * MGB + 19)) * 64 + kc) * 64 + t) * 8) = z;
  }
}

template <bool BF>
static __device__ __forceinline__ void prep_w_body(
    PrepWSmem& sm, const void* headW, const void* headb,
    const void* tailW, const void* tailb,
    short* Wfh, short* Wft, float* bias_h, float* bias_t, int kc, int which) {
  const void* W = which ? tailW : headW;
  short* Wf = which ? Wft : Wfh;
  int t = threadIdx.x;
  for (int e = t; e < 16 * EMB; e += 256) {
    int kk = e / EMB, c = e % EMB;
    sm.Ws[kk][c] = f2bfbits(ldf<BF>(W, (size_t)(kc * 16 + kk) * EMB + c));
  }
  __syncthreads();
  int lane = t & 63, cg0 = t >> 6;
  int rr = lane & 31, half = lane >> 5;
#pragma unroll
  for (int q = 0; q < 6; q++) {
    int cgi = cg0 + q * 4;
    int col = cgi * 32 + rr;
    s16x8 v;
#pragma unroll
    for (int tt = 0; tt < 8; tt++) v[tt] = sm.Ws[half * 8 + tt][col];
    *(s16x8*)(Wf + (((size_t)kc * 24 + cgi) * 64 + lane) * 8) = v;
  }
  if (kc == 0) {
    const void* bsrc = which ? tailb : headb;
    float* bdst = which ? bias_t : bias_h;
    for (int c = t; c < EMB; c += 256) bdst[c] = ldf<BF>(bsrc, c);
  }
}

template <bool BF>
static __device__ __forceinline__ void transpose_w_body(
    TwSmem& sm, const void* bilW, short* Wt, int s16i, int kb) {
  int t = threadIdx.x;
  size_t kbase = (size_t)kb * 4096 + s16i * 16;
  for (int e = t; e < 16 * NL; e += 256) {
    int rr = e / NL, l = e % NL;
    sm.Ws[rr][l] = ldf<BF>(bilW, (kbase + rr) * NL + l);
  }
  __syncthreads();
  int c = t >> 6, lane = t & 63;
  int half = lane >> 5, col = lane & 31;
  int label = c * 32 + col;
  s16x8 v;
#pragma unroll
  for (int tt = 0; tt < 8; tt++) {
    float x = (label < NL) ? sm.Ws[half * 8 + tt][label] : 0.f;
    v[tt] = f2bfbits(x);
  }
  size_t off = ((((size_t)kb * 256 + s16i) * 4 + c) * 64 + lane) * 8;
  *(s16x8*)(Wt + off) = v;
}

template <bool BF>
static __device__ __forceinline__ void stage1_dispatch(
    S1Smem& sm, const void* seq, const void* att, const int* midx,
    const void* mmask, const void* headW, const void* headb,
    const void* tailW, const void* tailb, const void* bilW,
    float* ent_emb, short* ent_att, short* Sf, short* Aht,
    short* Wfh, short* Wft, float* bias_h, float* bias_t,
    short* Wt, float* riskarr, int q) {
  if (q == 0 && threadIdx.x < 2) riskarr[threadIdx.x] = 0.f;  // [0]=sum [1]=ctr
  if (q < B * E * H) {
    ent_att_body<BF>(sm.a, att, midx, mmask, ent_att, q);
  } else if (q < B * E * H + B * E) {
    ent_emb_body<BF>(sm.e, seq, midx, mmask, ent_emb, q - B * E * H);
  } else if (q < B * E * H + B * E + 256) {
    int r = q - (B * E * H + B * E);
    prep_seq_body<BF>(sm.ps, seq, Sf, Aht, r & 63, r >> 6);
  } else if (q < B * E * H + B * E + 256 + 192) {
    int r = q - (B * E * H + B * E + 256);
    prep_w_body<BF>(sm.pw, headW, headb, tailW, tailb, Wfh, Wft,
                    bias_h, bias_t, r % 96, r / 96);
  } else {
    int r = q - (B * E * H + B * E + 256 + 192);
    transpose_w_body<BF>(sm.tw, bilW, Wt, r & 255, r >> 8);
  }
}

__global__ __launch_bounds__(256) void k_stage1(
    const void* seq, const void* att, const int* midx, const void* mmask,
    const void* headW, const void* headb, const void* tailW, const void* tailb,
    const void* bilW,
    float* ent_emb, short* ent_att, short* Sf, short* Aht,
    short* Wfh, short* Wft, float* bias_h, float* bias_t,
    short* Wt, float* riskarr) {
  __shared__ S1Smem sm;
  if (detect_bf(mmask))
    stage1_dispatch<true >(sm, seq, att, midx, mmask, headW, headb, tailW,
                           tailb, bilW, ent_emb, ent_att, Sf, Aht, Wfh, Wft,
                           bias_h, bias_t, Wt, riskarr, blockIdx.x);
  else
    stage1_dispatch<false>(sm, seq, att, midx, mmask, headW, headb, tailW,
                           tailb, bilW, ent_emb, ent_att, Sf, Aht, Wfh, Wft,
                           bias_h, bias_t, Wt, riskarr, blockIdx.x);
}

// ---------------------------------------------------------------------------
// Stage 2: ht_att (-> Aht fragments) + prep_ahs (-> Ahs/Ats). Tiny LDS.
// ---------------------------------------------------------------------------
static __device__ __forceinline__ void ht_att_body(
    float* red, const short* __restrict__ ent_att, const int* __restrict__ hts,
    short* __restrict__ Aht, int bp) {
  int b = bp / P, p = bp % P;
  int hi = hts[bp * 2 + 0], ti = hts[bp * 2 + 1];
  const short* hA = ent_att + ((size_t)(b * E + hi)) * H * C;
  const short* tA = ent_att + ((size_t)(b * E + ti)) * H * C;
  float v[2][2];
  float loc = 0.f;
#pragma unroll
  for (int q = 0; q < 2; q++) {
    int c = q * 512 + threadIdx.x * 2;
    float s0 = 0.f, s1 = 0.f;
#pragma unroll
    for (int h = 0; h < H; h++) {
      ushort2 a = *(const ushort2*)(hA + h * C + c);
      ushort2 t2 = *(const ushort2*)(tA + h * C + c);
      s0 += bf2f((short)a.x) * bf2f((short)t2.x);
      s1 += bf2f((short)a.y) * bf2f((short)t2.y);
    }
    v[q][0] = s0 * (1.0f / H);
    v[q][1] = s1 * (1.0f / H);
    loc += v[q][0] + v[q][1];
  }
#pragma unroll
  for (int off = 32; off > 0; off >>= 1) loc += __shfl_xor(loc, off, 64);
  if ((threadIdx.x & 63) == 0) red[threadIdx.x >> 6] = loc;
  __syncthreads();
  float inv = 1.0f / (red[0] + red[1] + red[2] + red[3] + 1e-5f);
  int mg = p >> 5, rr = p & 31;
#pragma unroll
  for (int q = 0; q < 2; q++) {
    int c = q * 512 + threadIdx.x * 2;
    int kc = c >> 4, half = (c >> 3) & 1, tt = c & 7;
    short* dst =
        Aht + ((((size_t)(b * MGB + mg)) * 64 + kc) * 64 + half * 32 + rr) * 8 + tt;
    dst[0] = f2bfbits(v[q][0] * inv);
    dst[1] = f2bfbits(v[q][1] * inv);
  }
}

static __device__ __forceinline__ void prep_ahs_body(
    const float* __restrict__ ent_emb, const int* __restrict__ hts,
    short* __restrict__ Ahs, short* __restrict__ Ats, int mg, int which) {
  short* Adst = which ? Ats : Ahs;
  int t = threadIdx.x, lane = t & 63, kc0 = t >> 6;
  int rr = lane & 31, half = lane >> 5;
  int row = mg * 32 + rr;
  bool valid = row < N;
  size_t base = 0;
  if (valid) {
    int b = row / P, p = row % P;
    int e = hts[(b * P + p) * 2 + which];
    base = (size_t)(b * E + e) * D;
  }
#pragma unroll
  for (int q = 0; q < 12; q++) {
    int kc = kc0 + q * 4;
    s16x8 v = {0, 0, 0, 0, 0, 0, 0, 0};
    if (valid) {
      const float* p = ent_emb + base + kc * 16 + half * 8;
      float4 v0 = *(const float4*)p;
      float4 v1 = *(const float4*)(p + 4);
      v[0] = f2bfbits(v0.x); v[1] = f2bfbits(v0.y);
      v[2] = f2bfbits(v0.z); v[3] = f2bfbits(v0.w);
      v[4] = f2bfbits(v1.x); v[5] = f2bfbits(v1.y);
      v[6] = f2bfbits(v1.z); v[7] = f2bfbits(v1.w);
    }
    *(s16x8*)(Adst + (((size_t)mg * 48 + kc) * 64 + lane) * 8) = v;
  }
}

__global__ __launch_bounds__(256) void k_stage2(
    const short* __restrict__ ent_att, const float* __restrict__ ent_emb,
    const int* __restrict__ hts,
    short* __restrict__ Aht, short* __restrict__ Ahs, short* __restrict__ Ats) {
  __shared__ float red[4];
  int q = blockIdx.x;
  if (q < B * P) {
    ht_att_body(red, ent_att, hts, Aht, q);
  } else {
    int r = q - B * P;
    prep_ahs_body(ent_emb, hts, Ahs, Ats, r % MG, r / MG);
  }
}

// ---------------------------------------------------------------------------
// Stage 3: rs = ht_att @ seq via MFMA 32x32x16 bf16 (+ Ars pad zero).
// Ars lives in the `part` region — no aliasing with Aht (race-free).
// ---------------------------------------------------------------------------
__global__ __launch_bounds__(256) void k_rs_mfma(
    const short* __restrict__ Aht, const short* __restrict__ Sf,
    short* __restrict__ Ars) {
  int mt = blockIdx.x, nt = blockIdx.y, b = blockIdx.z;
  int t = threadIdx.x, w = t >> 6, lane = t & 63;
  int half = lane >> 5, r = lane & 31;
  int wm = w >> 1, wn = w & 1;
  int mg = mt * 2 + wm;          // 0..19
  int cg0 = nt * 4 + wn * 2;     // 0..22, 2 cg per wave

  // zero Ars pad row-group mg=75: 48*64*8 = 24576 shorts, contiguous
  if (b == 0 && mt == 0) {
    int zt = nt * 256 + t;  // 0..1535
    s16x8 zz = {0, 0, 0, 0, 0, 0, 0, 0};
    for (int i = zt; i < 3072; i += 1536)
      *(s16x8*)(Ars + (size_t)1843200 + (size_t)i * 8) = zz;
  }

  f32x16 acc[2];
#pragma unroll
  for (int j = 0; j < 2; j++)
#pragma unroll
    for (int e = 0; e < 16; e++) acc[j][e] = 0.f;

  const short* abase = Aht + (((size_t)(b * MGB + mg)) * 64 * 64 + lane) * 8;
  const short* bbase = Sf + ((((size_t)(b * 64)) * 24 + cg0) * 64 + lane) * 8;

#pragma unroll 4
  for (int kc = 0; kc < 64; kc++) {
    s16x8 a  = *(const s16x8*)(abase + (size_t)kc * 64 * 8);
    s16x8 b0 = *(const s16x8*)(bbase + ((size_t)kc * 24 + 0) * 64 * 8);
    s16x8 b1 = *(const s16x8*)(bbase + ((size_t)kc * 24 + 1) * 64 * 8);
    acc[0] = __builtin_amdgcn_mfma_f32_32x32x16_bf16(a, b0, acc[0], 0, 0, 0);
    acc[1] = __builtin_amdgcn_mfma_f32_32x32x16_bf16(a, b1, acc[1], 0, 0, 0);
  }

  // C/D: col = lane&31, row = (reg&3) + 8*(reg>>2) + 4*half
#pragma unroll
  for (int j = 0; j < 2; j++) {
    int col = (cg0 + j) * 32 + r;
    int kcd = col >> 4, hd = (col >> 3) & 1, ttd = col & 7;
#pragma unroll
    for (int reg = 0; reg < 16; reg++) {
      int p = mg * 32 + (reg & 3) + 8 * (reg >> 2) + 4 * half;
      if (p < P) {
        int n = b * P + p;
        Ars[((((size_t)(n >> 5)) * 48 + kcd) * 64 + hd * 32 + (n & 31)) * 8 + ttd] =
            f2bfbits(acc[j][reg]);
      }
    }
  }
}

// ---------------------------------------------------------------------------
// Stage 4: hz/tz = tanh(A @ W + bias) via MFMA, output bf16.
// ---------------------------------------------------------------------------
__global__ __launch_bounds__(256) void k_head_mfma(
    const short* __restrict__ Ahs, const short* __restrict__ Ats,
    const short* __restrict__ Ars,
    const short* __restrict__ Wfh, const short* __restrict__ Wft,
    const float* __restrict__ bias_h, const float* __restrict__ bias_t,
    short* __restrict__ hz, short* __restrict__ tz) {
  int mt = blockIdx.x, nt = blockIdx.y, which = blockIdx.z;
  const short* Ahead = which ? Ats : Ahs;
  const short* Wf = which ? Wft : Wfh;
  const float* bias = which ? bias_t : bias_h;
  short* out = which ? tz : hz;

  int t = threadIdx.x, w = t >> 6, lane = t & 63;
  int half = lane >> 5, r = lane & 31;
  int wm = w >> 1, wn = w & 1;
  int mg0 = mt * 4 + wm * 2;
  int cg0 = nt * 4 + wn * 2;

  f32x16 acc[2][2];
#pragma unroll
  for (int i = 0; i < 2; i++)
#pragma unroll
    for (int j = 0; j < 2; j++)
#pragma unroll
      for (int e = 0; e < 16; e++) acc[i][j][e] = 0.f;

#pragma unroll 4
  for (int kc = 0; kc < 48; kc++) {
    s16x8 a0 = *(const s16x8*)(Ahead + (((size_t)(mg0 + 0) * 48 + kc) * 64 + lane) * 8);
    s16x8 a1 = *(const s16x8*)(Ahead + (((size_t)(mg0 + 1) * 48 + kc) * 64 + lane) * 8);
    s16x8 b0 = *(const s16x8*)(Wf + (((size_t)kc * 24 + cg0 + 0) * 64 + lane) * 8);
    s16x8 b1 = *(const s16x8*)(Wf + (((size_t)kc * 24 + cg0 + 1) * 64 + lane) * 8);
    acc[0][0] = __builtin_amdgcn_mfma_f32_32x32x16_bf16(a0, b0, acc[0][0], 0, 0, 0);
    acc[0][1] = __builtin_amdgcn_mfma_f32_32x32x16_bf16(a0, b1, acc[0][1], 0, 0, 0);
    acc[1][0] = __builtin_amdgcn_mfma_f32_32x32x16_bf16(a1, b0, acc[1][0], 0, 0, 0);
    acc[1][1] = __builtin_amdgcn_mfma_f32_32x32x16_bf16(a1, b1, acc[1][1], 0, 0, 0);
  }
#pragma unroll 4
  for (int kc = 0; kc < 48; kc++) {
    s16x8 a0 = *(const s16x8*)(Ars + (((size_t)(mg0 + 0) * 48 + kc) * 64 + lane) * 8);
    s16x8 a1 = *(const s16x8*)(Ars + (((size_t)(mg0 + 1) * 48 + kc) * 64 + lane) * 8);
    s16x8 b0 = *(const s16x8*)(Wf + (((size_t)(kc + 48) * 24 + cg0 + 0) * 64 + lane) * 8);
    s16x8 b1 = *(const s16x8*)(Wf + (((size_t)(kc + 48) * 24 + cg0 + 1) * 64 + lane) * 8);
    acc[0][0] = __builtin_amdgcn_mfma_f32_32x32x16_bf16(a0, b0, acc[0][0], 0, 0, 0);
    acc[0][1] = __builtin_amdgcn_mfma_f32_32x32x16_bf16(a0, b1, acc[0][1], 0, 0, 0);
    acc[1][0] = __builtin_amdgcn_mfma_f32_32x32x16_bf16(a1, b0, acc[1][0], 0, 0, 0);
    acc[1][1] = __builtin_amdgcn_mfma_f32_32x32x16_bf16(a1, b1, acc[1][1], 0, 0, 0);
  }

#pragma unroll
  for (int i = 0; i < 2; i++) {
    int rowbase = (mg0 + i) * 32 + 4 * half;
#pragma unroll
    for (int j = 0; j < 2; j++) {
      int col = (cg0 + j) * 32 + r;
      float bv = bias[col];
#pragma unroll
      for (int reg = 0; reg < 16; reg++) {
        int n = rowbase + (reg & 3) + 8 * (reg >> 2);
        if (n < N) out[(size_t)n * EMB + col] = f2bfbits(tanhf(acc[i][j][reg] + bv));
      }
    }
  }
}

// ---------------------------------------------------------------------------
// Stage 5: bilinear logits via MFMA (R3-measured single-tile version).
// Writes per-(kb,z) partials, no atomics.
// ---------------------------------------------------------------------------
__global__ __launch_bounds__(256) void k_logits_mfma(
    const short* __restrict__ hz, const short* __restrict__ tz,
    const short* __restrict__ Wt, float* __restrict__ part) {
  int kb = blockIdx.x;
  int mb = blockIdx.y;
  int z = blockIdx.z;  // i-half
  int t = threadIdx.x;
  int w = t >> 6, lane = t & 63;
  int half = lane >> 5, r = lane & 31;
  int nb = mb * 128;

  __shared__ float hzs[128][33];
  {
    int row = t >> 1;
    int col0 = (t & 1) * 16;
    int n = nb + row;
#pragma unroll
    for (int q = 0; q < 2; q++) {
      float vv[8] = {0.f, 0.f, 0.f, 0.f, 0.f, 0.f, 0.f, 0.f};
      if (n < N) {
        s16x8 v = *(const s16x8*)(hz + (size_t)n * EMB + kb * 64 + z * 32 + col0 + q * 8);
#pragma unroll
        for (int tt = 0; tt < 8; tt++) vv[tt] = bf2f(v[tt]);
      }
#pragma unroll
      for (int tt = 0; tt < 8; tt++) hzs[row][col0 + q * 8 + tt] = vv[tt];
    }
  }
  float tzr[4][8];
  {
    int n = nb + w * 32 + r;
#pragma unroll
    for (int q4 = 0; q4 < 4; q4++) {
      s16x8 v = {0, 0, 0, 0, 0, 0, 0, 0};
      if (n < N) v = *(const s16x8*)(tz + (size_t)n * EMB + kb * 64 + q4 * 16 + half * 8);
#pragma unroll
      for (int tt = 0; tt < 8; tt++) tzr[q4][tt] = bf2f(v[tt]);
    }
  }
  __syncthreads();

  f32x16 acc[4];
#pragma unroll
  for (int c = 0; c < 4; c++)
#pragma unroll
    for (int e = 0; e < 16; e++) acc[c][e] = 0.f;

  const int wrow = w * 32 + r;
  const short* wbase = Wt + (((size_t)kb * 256) * 4) * 64 * 8 + (size_t)lane * 8;

#pragma unroll 2
  for (int ii = 0; ii < 32; ii++) {
    int i = z * 32 + ii;
    float hv = hzs[wrow][ii];
#pragma unroll
    for (int q4 = 0; q4 < 4; q4++) {
      i32x4 pk;
#pragma unroll
      for (int u = 0; u < 4; u++)
        pk[u] = cvt_pk_bf16(hv * tzr[q4][2 * u], hv * tzr[q4][2 * u + 1]);
      s16x8 af = __builtin_bit_cast(s16x8, pk);
      int s16i = i * 4 + q4;
#pragma unroll
      for (int c = 0; c < 4; c++) {
        s16x8 bfv = *(const s16x8*)(wbase + ((size_t)s16i * 4 + c) * 64 * 8);
        acc[c] = __builtin_amdgcn_mfma_f32_32x32x16_bf16(af, bfv, acc[c], 0, 0, 0);
      }
    }
  }

  // unconditional partial stores: part[kb*2+z][n][label]
  float* pbase = part + ((size_t)(kb * 2 + z) * NPAD + nb + w * 32) * LPAD;
#pragma unroll
  for (int c = 0; c < 4; c++) {
    int label = c * 32 + r;
#pragma unroll
    for (int reg = 0; reg < 16; reg++) {
      int row = (reg & 3) + 8 * (reg >> 2) + 4 * half;
      pbase[(size_t)row * LPAD + label] = acc[c][reg];
    }
  }
}

// ---------------------------------------------------------------------------
// Stage 6: reduce 24 partials + bias -> final logits_f AND out[1..].
// ---------------------------------------------------------------------------
template <bool BF>
static __device__ __forceinline__ void reduce_body(
    const float* __restrict__ part, const void* bilb,
    float* __restrict__ logits_f, void* out, int blk) {
  int idx = blk * 256 + threadIdx.x;
  if (idx >= N * NL) return;
  int n = idx / NL, l = idx % NL;
  float s = ldf<BF>(bilb, l);
  const float* p = part + (size_t)n * LPAD + l;
#pragma unroll
  for (int k = 0; k < NKBZ; k++) s += p[(size_t)k * NPAD * LPAD];
  logits_f[idx] = s;
  stf<BF>(out, (size_t)idx + 1, s);  // out[0] = risk, out[1..] = logits
}

__global__ __launch_bounds__(256) void k_reduce(
    const float* __restrict__ part, const void* bilb, const void* mmask,
    float* __restrict__ logits_f, void* out) {
  if (detect_bf(mmask)) reduce_body<true >(part, bilb, logits_f, out, blockIdx.x);
  else                  reduce_body<false>(part, bilb, logits_f, out, blockIdx.x);
}

// ---------------------------------------------------------------------------
// Stage 7: per-relation PU risk; last block writes total into out[0].
// ---------------------------------------------------------------------------
template <bool BF>
static __device__ __forceinline__ void risk_body(
    RiskSmem& sm, const float* logits_f, const int* labels,
    const void* priors_l, const void* priors_o,
    void* out, float* risk_ws, int r) {
  int t = threadIdx.x;
  float s_neg = 0.f, s_pp = 0.f, s_pn = 0.f, c_neg = 0.f, c_pos = 0.f;
  for (int n = t; n < N; n += 256) {
    float sc = logits_f[(size_t)n * NL + (r + 1)] - logits_f[(size_t)n * NL];
    bool pos = labels[(size_t)n * NL + (r + 1)] == 1;
    float ln = 0.25f * (sc + 1.f) * (sc + 1.f);  // sign=-1
    float lp = 0.25f * (sc - 1.f) * (sc - 1.f);  // sign=+1
    if (pos) { c_pos += 1.f; s_pp += lp; s_pn += ln; }
    else     { c_neg += 1.f; s_neg += ln; }
  }
  sm.red[0][t] = s_neg; sm.red[1][t] = s_pp; sm.red[2][t] = s_pn;
  sm.red[3][t] = c_neg; sm.red[4][t] = c_pos;
  __syncthreads();
  for (int off = 128; off > 0; off >>= 1) {
    if (t < off) {
#pragma unroll
      for (int q = 0; q < 5; q++) sm.red[q][t] += sm.red[q][t + off];
    }
    __syncthreads();
  }
  if (t == 0) {
    float sq_neg   = sm.red[3][0] > 0.f ? sm.red[0][0] / fmaxf(sm.red[3][0], 1.f) : 0.f;
    float sq_pos_p = sm.red[4][0] > 0.f ? sm.red[1][0] / fmaxf(sm.red[4][0], 1.f) : 0.f;
    float sq_pos_n = sm.red[4][0] > 0.f ? sm.red[2][0] / fmaxf(sm.red[4][0], 1.f) : 0.f;
    float po = ldf<BF>(priors_o, r), pl = ldf<BF>(priors_l, r);
    float weight = sqrtf((1.f - po) / po);
    float pu = (po - pl) / (1.f - pl);
    float risk1 = (1.f - po) / (1.f - pu) * sq_neg - (pu - pu * po) / (1.f - pu) * sq_pos_n;
    float risk2 = po * sq_pos_p * weight;
    float riskv = (risk1 < 0.f) ? -risk1 : (risk1 + risk2);  // BETA=0, GAMMA=1
    atomicAdd(&risk_ws[0], riskv);
    __threadfence();
    unsigned prev = atomicAdd((unsigned int*)(risk_ws + 1), 1u);
    if (prev == RELS - 1) {
      __threadfence();
      float total = atomicAdd(&risk_ws[0], 0.0f);  // atomic read at coherent point
      stf<BF>(out, 0, total);
    }
  }
}

__global__ __launch_bounds__(256) void k_risk(
    const float* __restrict__ logits_f, const int* __restrict__ labels,
    const void* priors_l, const void* priors_o, const void* mmask,
    void* out, float* risk_ws) {
  __shared__ RiskSmem sm;
  if (detect_bf(mmask))
    risk_body<true >(sm, logits_f, labels, priors_l, priors_o, out, risk_ws, blockIdx.x);
  else
    risk_body<false>(sm, logits_f, labels, priors_l, priors_o, out, risk_ws, blockIdx.x);
}

// ---------------------------------------------------------------------------
extern "C" void kernel_launch(void* const* d_in, const int* in_sizes, int n_in,
                              void* d_out, int out_size, void* d_ws, size_t ws_size,
                              hipStream_t stream) {
  const void* seq    = d_in[0];
  const void* att    = d_in[1];
  const int*  midx   = (const int*)d_in[2];
  const void* mmask  = d_in[3];
  const int*  hts    = (const int*)d_in[4];
  const int*  labels = (const int*)d_in[5];
  const void* pl     = d_in[6];
  const void* po     = d_in[7];
  const void* headW  = d_in[8];
  const void* headb  = d_in[9];
  const void* tailW  = d_in[10];
  const void* tailb  = d_in[11];
  const void* bilW   = d_in[12];
  const void* bilb   = d_in[13];

  // Workspace layout (floats after 64B header); ~78 MB total.
  // regionA = [ent_att(bf16) | Aht | Sf]; all dead after k_rs_mfma.
  // Ars aliases `part` (dead until k_logits writes it) — no Aht overlap.
  float* w = (float*)d_ws + 16;
  float* ent_emb  = w;                                     //    92,160 f
  short* hz       = (short*)(ent_emb + (size_t)B * E * D); // 1,843,200 s
  short* tz       = hz + (size_t)N * EMB;                  // 1,843,200 s
  float* logits_f = (float*)(tz + (size_t)N * EMB);        //   232,800 f
  float* riskarr  = logits_f + (size_t)N * NL;             //       128 f
  float* bias_h   = riskarr + 128;                         //       768 f
  float* bias_t   = bias_h + 768;                          //       768 f
  float* regionA  = bias_t + 768;                          // 3,620,864 f
  short* ent_att  = (short*)regionA;                       // 1,474,560 s (bf16)
  short* Aht      = ent_att + 1474560;                     // 2,621,440 s
  short* Sf       = Aht + (size_t)B * MGB * 64 * 512;      // 3,145,728 s
  float* after    = regionA + 3620864;
  short* Ahs      = (short*)after;                         // 1,867,776 s
  short* Ats      = Ahs + (size_t)MG * 48 * 512;           // 1,867,776 s
  short* Wfh      = Ats + (size_t)MG * 48 * 512;           // 1,179,648 s
  short* Wft      = Wfh + (size_t)96 * 24 * 512;           // 1,179,648 s
  float* after2   = after + 3047424;
  short* Wt       = (short*)after2;                        // 6,291,456 s
  float* part     = after2 + 3145728;                      // 7,471,104 f
  short* Ars      = (short*)part;                          // 1,867,776 s (alias, dead by stage 5)

  // 7 launches; all input-only prep front-loaded into stage1.
  k_stage1<<<NB_S1, 256, 0, stream>>>(
      seq, att, midx, mmask, headW, headb, tailW, tailb, bilW,
      ent_emb, ent_att, Sf, Aht, Wfh, Wft, bias_h, bias_t, Wt, riskarr);
  k_stage2<<<NB_S2, 256, 0, stream>>>(ent_att, ent_emb, hts, Aht, Ahs, Ats);
  k_rs_mfma<<<dim3(10, 6, B), 256, 0, stream>>>(Aht, Sf, Ars);
  k_head_mfma<<<dim3(19, 6, 2), 256, 0, stream>>>(Ahs, Ats, Ars, Wfh, Wft,
                                                  bias_h, bias_t, hz, tz);
  k_logits_mfma<<<dim3(12, 19, 2), 256, 0, stream>>>(hz, tz, Wt, part);
  k_reduce<<<NB_RD, 256, 0, stream>>>(part, bilb, mmask, logits_f, d_out);
  k_risk<<<RELS, 256, 0, stream>>>(logits_f, labels, pl, po, mmask,
                                   d_out, riskarr);
}